// Round 4
// baseline (541.238 us; speedup 1.0000x reference)
//
#include <hip/hip_runtime.h>
#include <hip/hip_bf16.h>
#include <stdint.h>

#define T_TOK 4096
#define H_DIM 1024
#define F_DIM 2816
#define E_NUM 8

typedef __attribute__((ext_vector_type(8))) __bf16 bf16x8;
typedef __attribute__((ext_vector_type(4))) float floatx4;
typedef __attribute__((address_space(3))) char lds_char;
typedef __attribute__((address_space(1))) const char glb_char;

// async 16B global->LDS (dest = wave-uniform base + lane*16)
__device__ __forceinline__ void gload16(const void* g, void* l) {
  __builtin_amdgcn_global_load_lds((glb_char*)g, (lds_char*)l, 16, 0, 0);
}

// round-to-nearest-even fp32 -> bf16, packed 2-at-a-time
__device__ __forceinline__ unsigned pack2bf16(float a, float b) {
  unsigned ua = __builtin_bit_cast(unsigned, a);
  unsigned ub = __builtin_bit_cast(unsigned, b);
  ua += 0x7fffu + ((ua >> 16) & 1u);
  ub += 0x7fffu + ((ub >> 16) & 1u);
  return (ua >> 16) | (ub & 0xffff0000u);
}

// XOR swizzle for [row][64 bf16] LDS tiles (128 B rows) — fallback kernels.
__device__ __forceinline__ int swz(int row, int colb) {
  return (row * 128 + colb) ^ ((row & 7) << 4);
}

// ---------------- fp32 -> bf16 weight conversion (grid-stride) --------------
__global__ __launch_bounds__(256) void convert_kernel(
    const float* __restrict__ src, __hip_bfloat16* __restrict__ dst,
    int nchunk8) {
  int i = blockIdx.x * blockDim.x + threadIdx.x;
  const int stride = gridDim.x * blockDim.x;
  for (; i < nchunk8; i += stride) {
    const float4* s = (const float4*)(src + (size_t)i * 8);
    float4 a = s[0], b = s[1];
    uint4 p;
    p.x = pack2bf16(a.x, a.y); p.y = pack2bf16(a.z, a.w);
    p.z = pack2bf16(b.x, b.y); p.w = pack2bf16(b.z, b.w);
    *(uint4*)((char*)dst + (size_t)i * 16) = p;
  }
}

// ---------------- router ----------------------------------------------------
__global__ __launch_bounds__(256) void router_kernel(
    const float* __restrict__ x, const float* __restrict__ gate,
    float* __restrict__ logits_out, __hip_bfloat16* __restrict__ xb,
    int* __restrict__ counts, int* __restrict__ idx_list,
    float* __restrict__ wgt_list)
{
  const int wv = threadIdx.x >> 6;
  const int lane = threadIdx.x & 63;
  const int t = blockIdx.x * 4 + wv;

  const float4* xr = (const float4*)(x + (size_t)t * H_DIM);
  const float4* g4 = (const float4*)gate;

  float acc[E_NUM];
#pragma unroll
  for (int e = 0; e < E_NUM; ++e) acc[e] = 0.f;

  unsigned* xbo = (unsigned*)(xb + (size_t)t * H_DIM);
#pragma unroll
  for (int j = 0; j < 4; ++j) {
    int i = j * 64 + lane;
    float4 xv = xr[i];
    uint2 pk;
    pk.x = pack2bf16(xv.x, xv.y);
    pk.y = pack2bf16(xv.z, xv.w);
    *(uint2*)(xbo + i * 2) = pk;
#pragma unroll
    for (int e = 0; e < E_NUM; ++e) {
      float4 gv = g4[e * 256 + i];
      acc[e] += xv.x * gv.x + xv.y * gv.y + xv.z * gv.z + xv.w * gv.w;
    }
  }
#pragma unroll
  for (int off = 32; off > 0; off >>= 1) {
#pragma unroll
    for (int e = 0; e < E_NUM; ++e) acc[e] += __shfl_xor(acc[e], off, 64);
  }

  if (lane == 0) {
#pragma unroll
    for (int e = 0; e < E_NUM; ++e) logits_out[(size_t)t * E_NUM + e] = acc[e];
    int i0 = 0; float v0 = acc[0];
#pragma unroll
    for (int e = 1; e < E_NUM; ++e) if (acc[e] > v0) { v0 = acc[e]; i0 = e; }
    int i1 = -1; float v1 = -1e30f;
#pragma unroll
    for (int e = 0; e < E_NUM; ++e)
      if (e != i0 && acc[e] > v1) { v1 = acc[e]; i1 = e; }
    float p1 = __expf(v1 - v0);
    float w0 = 1.f / (1.f + p1);
    float w1 = p1 / (1.f + p1);
    int pos0 = atomicAdd(&counts[i0], 1);
    idx_list[i0 * T_TOK + pos0] = t;
    wgt_list[i0 * T_TOK + pos0] = w0;
    int pos1 = atomicAdd(&counts[i1], 1);
    idx_list[i1 * T_TOK + pos1] = t;
    wgt_list[i1 * T_TOK + pos1] = w1;
  }
}

__global__ void scan_kernel(const int* __restrict__ counts,
                            int* __restrict__ offsets) {
  if (threadIdx.x == 0) {
    int s = 0;
    for (int e = 0; e < E_NUM; ++e) { offsets[e] = s; s += counts[e]; }
  }
}

// ------------- GEMM1 (2-phase dbuf, BK=32, counted vmcnt) -------------------
// hidden = silu(X W1^T) * (X W3^T); all operands bf16.
// LDS tile [128 rows][32 bf16] (64 B rows); chunk swizzle: lin = chunk^(row&3).
__global__ __launch_bounds__(256) void gemm1_kernel(
    const __hip_bfloat16* __restrict__ xb,
    const __hip_bfloat16* __restrict__ w1b,
    const __hip_bfloat16* __restrict__ w3b,
    const int* __restrict__ counts, const int* __restrict__ offsets,
    const int* __restrict__ idx_list, __hip_bfloat16* __restrict__ hidden)
{
  const int e = blockIdx.z;
  const int n_e = counts[e];
  const int tm = blockIdx.y;
  if (n_e == 0 || tm * 128 >= n_e) return;
  const int tn = blockIdx.x;
  const int f0 = tn * 128;
  const int off_e = offsets[e];

  __shared__ char lds[49152];          // [A|B1|B3] x [2 sets] x 8192
  char* sA  = lds;
  char* sB1 = lds + 16384;
  char* sB3 = lds + 32768;

  const int tid = threadIdx.x;
  const int lane = tid & 63;
  const int wv = tid >> 6;
  const int wrow = (wv >> 1) * 64;
  const int wcol = (wv & 1) * 64;

  // staging: call c covers LDS rows wv*16 + c*64 + (lane>>2), chunk lane&3.
  // source chunk pre-swizzled so linear DMA + swizzled read match.
  const int csw = ((lane & 3) ^ ((lane >> 2) & 3)) << 4;
  const int r0 = wv * 16 + (lane >> 2);
  const int r1 = r0 + 64;
  const int l0 = wv * 1024;            // wave-uniform LDS offset, call 0
  const int l1 = wv * 1024 + 4096;     // call 1

  int p0 = tm * 128 + r0; p0 = p0 < n_e ? p0 : n_e - 1;
  int p1 = tm * 128 + r1; p1 = p1 < n_e ? p1 : n_e - 1;
  const size_t arow0 = (size_t)idx_list[e * T_TOK + p0] * 2048;
  const size_t arow1 = (size_t)idx_list[e * T_TOK + p1] * 2048;
  const char* xbp = (const char*)xb;
  const char* w1p = (const char*)w1b + ((size_t)e * F_DIM + f0) * 2048;
  const char* w3p = (const char*)w3b + ((size_t)e * F_DIM + f0) * 2048;
  const size_t b0 = (size_t)r0 * 2048;
  const size_t b1 = (size_t)r1 * 2048;

  floatx4 acc1[4][4], acc3[4][4];
#pragma unroll
  for (int m = 0; m < 4; ++m)
#pragma unroll
    for (int n = 0; n < 4; ++n)
#pragma unroll
      for (int r = 0; r < 4; ++r) { acc1[m][n][r] = 0.f; acc3[m][n][r] = 0.f; }

#define STAGE1(set, kb)                                     \
  do { char* dA = sA + (set) * 8192;                        \
       char* dB1 = sB1 + (set) * 8192;                      \
       char* dB3 = sB3 + (set) * 8192;                      \
       gload16(xbp + arow0 + (kb) + csw, dA + l0);          \
       gload16(xbp + arow1 + (kb) + csw, dA + l1);          \
       gload16(w1p + b0 + (kb) + csw, dB1 + l0);            \
       gload16(w1p + b1 + (kb) + csw, dB1 + l1);            \
       gload16(w3p + b0 + (kb) + csw, dB3 + l0);            \
       gload16(w3p + b1 + (kb) + csw, dB3 + l1); } while (0)

  // drain prologue gather loads so counted vmcnt below sees only DMAs
  asm volatile("s_waitcnt vmcnt(0)" ::: "memory");
  STAGE1(0, 0);

  const int cread = ((lane >> 4) ^ (lane & 3)) << 4;
  const int ard = (wrow + (lane & 15)) * 64 + cread;   // + m*1024
  const int brd = (wcol + (lane & 15)) * 64 + cread;   // + n*1024

#pragma unroll 2
  for (int kt = 0; kt < H_DIM / 32; ++kt) {            // 32 K-steps
    const int cur = kt & 1;
    if (kt < H_DIM / 32 - 1) {
      STAGE1(cur ^ 1, (kt + 1) * 64);
      asm volatile("s_waitcnt vmcnt(6)" ::: "memory"); // cur-set done; 6 fly
    } else {
      asm volatile("s_waitcnt vmcnt(0)" ::: "memory");
    }
    __syncthreads();
    const char* rA  = sA  + cur * 8192;
    const char* rB1 = sB1 + cur * 8192;
    const char* rB3 = sB3 + cur * 8192;
    bf16x8 af[4], bx1[4], bx3[4];
#pragma unroll
    for (int m = 0; m < 4; ++m)
      af[m] = *(const bf16x8*)(rA + ard + m * 1024);
#pragma unroll
    for (int n = 0; n < 4; ++n) {
      bx1[n] = *(const bf16x8*)(rB1 + brd + n * 1024);
      bx3[n] = *(const bf16x8*)(rB3 + brd + n * 1024);
    }
#pragma unroll
    for (int m = 0; m < 4; ++m)
#pragma unroll
      for (int n = 0; n < 4; ++n) {
        acc1[m][n] = __builtin_amdgcn_mfma_f32_16x16x32_bf16(
            af[m], bx1[n], acc1[m][n], 0, 0, 0);
        acc3[m][n] = __builtin_amdgcn_mfma_f32_16x16x32_bf16(
            af[m], bx3[n], acc3[m][n], 0, 0, 0);
      }
    __syncthreads();
  }
#undef STAGE1

#pragma unroll
  for (int m = 0; m < 4; ++m) {
#pragma unroll
    for (int r = 0; r < 4; ++r) {
      int rl = wrow + m * 16 + ((lane >> 4) << 2) + r;
      int pos = tm * 128 + rl;
      if (pos < n_e) {
        __hip_bfloat16* hrow = hidden + (size_t)(off_e + pos) * F_DIM + f0;
#pragma unroll
        for (int n = 0; n < 4; ++n) {
          float h1 = acc1[m][n][r];
          float h3 = acc3[m][n][r];
          float h = (h1 / (1.f + __expf(-h1))) * h3;   // silu(h1) * h3
          hrow[wcol + n * 16 + (lane & 15)] = __float2bfloat16(h);
        }
      }
    }
  }
}

// ------------- GEMM2 (2-phase dbuf, BK=32, counted vmcnt) -------------------
// y = hidden @ W2^T, scale by combine weight, atomicAdd scatter into out.
__global__ __launch_bounds__(256) void gemm2_kernel(
    const __hip_bfloat16* __restrict__ hidden,
    const __hip_bfloat16* __restrict__ w2b,
    const int* __restrict__ counts, const int* __restrict__ offsets,
    const int* __restrict__ idx_list, const float* __restrict__ wgt_list,
    float* __restrict__ out)
{
  const int e = blockIdx.z;
  const int n_e = counts[e];
  const int tm = blockIdx.y;
  if (n_e == 0 || tm * 128 >= n_e) return;
  const int tn = blockIdx.x;
  const int n0 = tn * 128;
  const int off_e = offsets[e];

  __shared__ char lds[32768];          // [A|B] x [2 sets] x 8192
  char* sA = lds;
  char* sB = lds + 16384;
  __shared__ int s_tok[128];
  __shared__ float s_wgt[128];

  const int tid = threadIdx.x;
  if (tid < 128) {
    int pos = tm * 128 + tid;
    if (pos < n_e) {
      s_tok[tid] = idx_list[e * T_TOK + pos];
      s_wgt[tid] = wgt_list[e * T_TOK + pos];
    } else {
      s_tok[tid] = -1;
      s_wgt[tid] = 0.f;
    }
  }

  const int lane = tid & 63;
  const int wv = tid >> 6;
  const int wrow = (wv >> 1) * 64;
  const int wcol = (wv & 1) * 64;

  const int csw = ((lane & 3) ^ ((lane >> 2) & 3)) << 4;
  const int r0 = wv * 16 + (lane >> 2);
  const int r1 = r0 + 64;
  const int l0 = wv * 1024;
  const int l1 = wv * 1024 + 4096;

  int p0 = tm * 128 + r0; p0 = p0 < n_e ? p0 : n_e - 1;
  int p1 = tm * 128 + r1; p1 = p1 < n_e ? p1 : n_e - 1;
  const size_t arow0 = (size_t)(off_e + p0) * (F_DIM * 2);
  const size_t arow1 = (size_t)(off_e + p1) * (F_DIM * 2);
  const char* hp = (const char*)hidden;
  const char* w2p = (const char*)w2b + ((size_t)e * H_DIM + n0) * (F_DIM * 2);
  const size_t b0 = (size_t)r0 * (F_DIM * 2);
  const size_t b1 = (size_t)r1 * (F_DIM * 2);

  floatx4 acc[4][4];
#pragma unroll
  for (int m = 0; m < 4; ++m)
#pragma unroll
    for (int n = 0; n < 4; ++n)
#pragma unroll
      for (int r = 0; r < 4; ++r) acc[m][n][r] = 0.f;

#define STAGE2(set, kb)                                     \
  do { char* dA = sA + (set) * 8192;                        \
       char* dB = sB + (set) * 8192;                        \
       gload16(hp + arow0 + (kb) + csw, dA + l0);           \
       gload16(hp + arow1 + (kb) + csw, dA + l1);           \
       gload16(w2p + b0 + (kb) + csw, dB + l0);             \
       gload16(w2p + b1 + (kb) + csw, dB + l1); } while (0)

  // drain prologue gather loads (s_tok/s_wgt) before counted-vmcnt pipeline
  asm volatile("s_waitcnt vmcnt(0)" ::: "memory");
  STAGE2(0, 0);

  const int cread = ((lane >> 4) ^ (lane & 3)) << 4;
  const int ard = (wrow + (lane & 15)) * 64 + cread;
  const int brd = (wcol + (lane & 15)) * 64 + cread;

#pragma unroll 2
  for (int kt = 0; kt < F_DIM / 32; ++kt) {            // 88 K-steps
    const int cur = kt & 1;
    if (kt < F_DIM / 32 - 1) {
      STAGE2(cur ^ 1, (kt + 1) * 64);
      asm volatile("s_waitcnt vmcnt(4)" ::: "memory");
    } else {
      asm volatile("s_waitcnt vmcnt(0)" ::: "memory");
    }
    __syncthreads();
    const char* rA = sA + cur * 8192;
    const char* rB = sB + cur * 8192;
    bf16x8 af[4], bx[4];
#pragma unroll
    for (int m = 0; m < 4; ++m)
      af[m] = *(const bf16x8*)(rA + ard + m * 1024);
#pragma unroll
    for (int n = 0; n < 4; ++n)
      bx[n] = *(const bf16x8*)(rB + brd + n * 1024);
#pragma unroll
    for (int m = 0; m < 4; ++m)
#pragma unroll
      for (int n = 0; n < 4; ++n)
        acc[m][n] = __builtin_amdgcn_mfma_f32_16x16x32_bf16(
            af[m], bx[n], acc[m][n], 0, 0, 0);
    __syncthreads();
  }
#undef STAGE2

#pragma unroll
  for (int m = 0; m < 4; ++m) {
#pragma unroll
    for (int r = 0; r < 4; ++r) {
      int rl = wrow + m * 16 + ((lane >> 4) << 2) + r;
      int tok = s_tok[rl];
      if (tok >= 0) {
        float wgt = s_wgt[rl];
        float* orow = out + (size_t)tok * H_DIM + n0;
#pragma unroll
        for (int n = 0; n < 4; ++n)
          atomicAdd(&orow[wcol + n * 16 + (lane & 15)], wgt * acc[m][n][r]);
      }
    }
  }
}

// =================== fallback path (round-1 kernels, fused convert) =========
__global__ __launch_bounds__(256) void gemm1_fb(
    const __hip_bfloat16* __restrict__ xb,
    const float* __restrict__ w1, const float* __restrict__ w3,
    const int* __restrict__ counts, const int* __restrict__ offsets,
    const int* __restrict__ idx_list, __hip_bfloat16* __restrict__ hidden)
{
  const int e = blockIdx.z;
  const int n_e = counts[e];
  const int tm = blockIdx.y;
  if (n_e == 0 || tm * 128 >= n_e) return;
  const int tn = blockIdx.x;
  const int f0 = tn * 128;
  const int off_e = offsets[e];

  __shared__ short sA[128 * 64];
  __shared__ short sB1[128 * 64];
  __shared__ short sB3[128 * 64];
  __shared__ int s_row[128];

  const int tid = threadIdx.x;
  if (tid < 128) {
    int pos = tm * 128 + tid;
    int p = pos < n_e ? pos : n_e - 1;
    s_row[tid] = idx_list[e * T_TOK + p];
  }
  const int lane = tid & 63;
  const int wv = tid >> 6;
  const int wrow = (wv >> 1) * 64;
  const int wcol = (wv & 1) * 64;
  const int cc = tid & 7;
  const int rbase = tid >> 3;

  floatx4 acc1[4][4], acc3[4][4];
#pragma unroll
  for (int m = 0; m < 4; ++m)
#pragma unroll
    for (int n = 0; n < 4; ++n)
#pragma unroll
      for (int r = 0; r < 4; ++r) { acc1[m][n][r] = 0.f; acc3[m][n][r] = 0.f; }

  const float* w1e = w1 + (size_t)e * F_DIM * H_DIM + (size_t)f0 * H_DIM;
  const float* w3e = w3 + (size_t)e * F_DIM * H_DIM + (size_t)f0 * H_DIM;

  for (int kt = 0; kt < H_DIM / 64; ++kt) {
    const int k0 = kt * 64;
    __syncthreads();
#pragma unroll
    for (int i = 0; i < 4; ++i) {
      int r = rbase + 32 * i;
      uint4 av = *(const uint4*)(xb + (size_t)s_row[r] * H_DIM + k0 + cc * 8);
      *(uint4*)((char*)sA + swz(r, cc * 16)) = av;
      const float4* p1 = (const float4*)(w1e + (size_t)r * H_DIM + k0 + cc * 8);
      float4 a1 = p1[0], b1 = p1[1];
      uint4 pb1;
      pb1.x = pack2bf16(a1.x, a1.y); pb1.y = pack2bf16(a1.z, a1.w);
      pb1.z = pack2bf16(b1.x, b1.y); pb1.w = pack2bf16(b1.z, b1.w);
      *(uint4*)((char*)sB1 + swz(r, cc * 16)) = pb1;
      const float4* p3 = (const float4*)(w3e + (size_t)r * H_DIM + k0 + cc * 8);
      float4 a3 = p3[0], b3 = p3[1];
      uint4 pb3;
      pb3.x = pack2bf16(a3.x, a3.y); pb3.y = pack2bf16(a3.z, a3.w);
      pb3.z = pack2bf16(b3.x, b3.y); pb3.w = pack2bf16(b3.z, b3.w);
      *(uint4*)((char*)sB3 + swz(r, cc * 16)) = pb3;
    }
    __syncthreads();
#pragma unroll
    for (int kk = 0; kk < 2; ++kk) {
      const int colb = kk * 64 + (lane >> 4) * 16;
      bf16x8 af[4], bf1[4], bf3[4];
#pragma unroll
      for (int m = 0; m < 4; ++m)
        af[m] = *(const bf16x8*)((const char*)sA +
                                 swz(wrow + m * 16 + (lane & 15), colb));
#pragma unroll
      for (int n = 0; n < 4; ++n) {
        bf1[n] = *(const bf16x8*)((const char*)sB1 +
                                  swz(wcol + n * 16 + (lane & 15), colb));
        bf3[n] = *(const bf16x8*)((const char*)sB3 +
                                  swz(wcol + n * 16 + (lane & 15), colb));
      }
#pragma unroll
      for (int m = 0; m < 4; ++m)
#pragma unroll
        for (int n = 0; n < 4; ++n) {
          acc1[m][n] = __builtin_amdgcn_mfma_f32_16x16x32_bf16(
              af[m], bf1[n], acc1[m][n], 0, 0, 0);
          acc3[m][n] = __builtin_amdgcn_mfma_f32_16x16x32_bf16(
              af[m], bf3[n], acc3[m][n], 0, 0, 0);
        }
    }
  }
#pragma unroll
  for (int m = 0; m < 4; ++m) {
#pragma unroll
    for (int r = 0; r < 4; ++r) {
      int rl = wrow + m * 16 + ((lane >> 4) << 2) + r;
      int pos = tm * 128 + rl;
      if (pos < n_e) {
        __hip_bfloat16* hrow = hidden + (size_t)(off_e + pos) * F_DIM + f0;
#pragma unroll
        for (int n = 0; n < 4; ++n) {
          float h1 = acc1[m][n][r];
          float h3 = acc3[m][n][r];
          float h = (h1 / (1.f + __expf(-h1))) * h3;
          hrow[wcol + n * 16 + (lane & 15)] = __float2bfloat16(h);
        }
      }
    }
  }
}

__global__ __launch_bounds__(256) void gemm2_fb(
    const __hip_bfloat16* __restrict__ hidden, const float* __restrict__ w2,
    const int* __restrict__ counts, const int* __restrict__ offsets,
    const int* __restrict__ idx_list, const float* __restrict__ wgt_list,
    float* __restrict__ out)
{
  const int e = blockIdx.z;
  const int n_e = counts[e];
  const int tm = blockIdx.y;
  if (n_e == 0 || tm * 128 >= n_e) return;
  const int tn = blockIdx.x;
  const int n0 = tn * 128;
  const int off_e = offsets[e];

  __shared__ short sA[128 * 64];
  __shared__ short sB[128 * 64];
  __shared__ int s_tok[128];
  __shared__ float s_wgt[128];

  const int tid = threadIdx.x;
  if (tid < 128) {
    int pos = tm * 128 + tid;
    if (pos < n_e) {
      s_tok[tid] = idx_list[e * T_TOK + pos];
      s_wgt[tid] = wgt_list[e * T_TOK + pos];
    } else {
      s_tok[tid] = -1;
      s_wgt[tid] = 0.f;
    }
  }
  const int lane = tid & 63;
  const int wv = tid >> 6;
  const int wrow = (wv >> 1) * 64;
  const int wcol = (wv & 1) * 64;
  const int cc = tid & 7;
  const int rbase = tid >> 3;

  floatx4 acc[4][4];
#pragma unroll
  for (int m = 0; m < 4; ++m)
#pragma unroll
    for (int n = 0; n < 4; ++n)
#pragma unroll
      for (int r = 0; r < 4; ++r) acc[m][n][r] = 0.f;

  const float* w2e = w2 + (size_t)e * H_DIM * F_DIM + (size_t)n0 * F_DIM;

  for (int kt = 0; kt < F_DIM / 64; ++kt) {
    const int k0 = kt * 64;
    __syncthreads();
#pragma unroll
    for (int i = 0; i < 4; ++i) {
      int r = rbase + 32 * i;
      int pos = tm * 128 + r;
      int pr = pos < n_e ? pos : n_e - 1;
      uint4 av = *(const uint4*)(hidden + (size_t)(off_e + pr) * F_DIM +
                                 k0 + cc * 8);
      *(uint4*)((char*)sA + swz(r, cc * 16)) = av;
      const float4* pb = (const float4*)(w2e + (size_t)r * F_DIM + k0 + cc * 8);
      float4 ba = pb[0], bb = pb[1];
      uint4 pk;
      pk.x = pack2bf16(ba.x, ba.y); pk.y = pack2bf16(ba.z, ba.w);
      pk.z = pack2bf16(bb.x, bb.y); pk.w = pack2bf16(bb.z, bb.w);
      *(uint4*)((char*)sB + swz(r, cc * 16)) = pk;
    }
    __syncthreads();
#pragma unroll
    for (int kk = 0; kk < 2; ++kk) {
      const int colb = kk * 64 + (lane >> 4) * 16;
      bf16x8 af[4], bf[4];
#pragma unroll
      for (int m = 0; m < 4; ++m)
        af[m] = *(const bf16x8*)((const char*)sA +
                                 swz(wrow + m * 16 + (lane & 15), colb));
#pragma unroll
      for (int n = 0; n < 4; ++n)
        bf[n] = *(const bf16x8*)((const char*)sB +
                                 swz(wcol + n * 16 + (lane & 15), colb));
#pragma unroll
      for (int m = 0; m < 4; ++m)
#pragma unroll
        for (int n = 0; n < 4; ++n)
          acc[m][n] = __builtin_amdgcn_mfma_f32_16x16x32_bf16(
              af[m], bf[n], acc[m][n], 0, 0, 0);
    }
  }
#pragma unroll
  for (int m = 0; m < 4; ++m) {
#pragma unroll
    for (int r = 0; r < 4; ++r) {
      int rl = wrow + m * 16 + ((lane >> 4) << 2) + r;
      int tok = s_tok[rl];
      if (tok >= 0) {
        float wgt = s_wgt[rl];
        float* orow = out + (size_t)tok * H_DIM + n0;
#pragma unroll
        for (int n = 0; n < 4; ++n)
          atomicAdd(&orow[wcol + n * 16 + (lane & 15)], wgt * acc[m][n][r]);
      }
    }
  }
}

extern "C" void kernel_launch(void* const* d_in, const int* in_sizes, int n_in,
                              void* d_out, int out_size, void* d_ws,
                              size_t ws_size, hipStream_t stream) {
  const float* x = (const float*)d_in[0];
  const float* gate = (const float*)d_in[1];
  const float* w1 = (const float*)d_in[2];
  const float* w3 = (const float*)d_in[3];
  const float* w2 = (const float*)d_in[4];

  float* out = (float*)d_out;                        // [T, H]
  float* logits = out + (size_t)T_TOK * H_DIM;       // [T, E]

  char* ws = (char*)d_ws;
  const size_t WEB = (size_t)E_NUM * F_DIM * H_DIM * 2;  // bf16 weight bytes
  const size_t o_idx = 256;
  const size_t o_wgt = o_idx + (size_t)E_NUM * T_TOK * 4;
  const size_t o_xb  = o_wgt + (size_t)E_NUM * T_TOK * 4;   // 16B aligned
  const size_t o_hid = o_xb + (size_t)T_TOK * H_DIM * 2;
  const size_t o_w1b = o_hid + (size_t)2 * T_TOK * F_DIM * 2;
  const size_t o_w3b = o_w1b + WEB;
  const size_t o_w2b = o_w3b + WEB;
  const size_t need  = o_w2b + WEB;                         // ~193 MB

  int* counts = (int*)ws;
  int* offsets = counts + 8;
  int* idx_list = (int*)(ws + o_idx);
  float* wgt_list = (float*)(ws + o_wgt);
  __hip_bfloat16* xb = (__hip_bfloat16*)(ws + o_xb);
  __hip_bfloat16* hidden = (__hip_bfloat16*)(ws + o_hid);

  hipMemsetAsync(counts, 0, 64, stream);
  hipMemsetAsync(out, 0, (size_t)T_TOK * H_DIM * sizeof(float), stream);

  if (ws_size >= need) {
    __hip_bfloat16* w1b = (__hip_bfloat16*)(ws + o_w1b);
    __hip_bfloat16* w3b = (__hip_bfloat16*)(ws + o_w3b);
    __hip_bfloat16* w2b = (__hip_bfloat16*)(ws + o_w2b);

    const int NCH = E_NUM * F_DIM * H_DIM / 8;
    convert_kernel<<<2048, 256, 0, stream>>>(w1, w1b, NCH);
    convert_kernel<<<2048, 256, 0, stream>>>(w3, w3b, NCH);
    convert_kernel<<<2048, 256, 0, stream>>>(w2, w2b, NCH);
    router_kernel<<<T_TOK / 4, 256, 0, stream>>>(x, gate, logits, xb, counts,
                                                 idx_list, wgt_list);
    scan_kernel<<<1, 64, 0, stream>>>(counts, offsets);
    gemm1_kernel<<<dim3(F_DIM / 128, T_TOK / 128, E_NUM), 256, 0, stream>>>(
        xb, w1b, w3b, counts, offsets, idx_list, hidden);
    gemm2_kernel<<<dim3(H_DIM / 128, T_TOK / 128, E_NUM), 256, 0, stream>>>(
        hidden, w2b, counts, offsets, idx_list, wgt_list, out);
  } else {
    router_kernel<<<T_TOK / 4, 256, 0, stream>>>(x, gate, logits, xb, counts,
                                                 idx_list, wgt_list);
    scan_kernel<<<1, 64, 0, stream>>>(counts, offsets);
    gemm1_fb<<<dim3(F_DIM / 128, T_TOK / 128, E_NUM), 256, 0, stream>>>(
        xb, w1, w3, counts, offsets, idx_list, hidden);
    gemm2_fb<<<dim3(H_DIM / 128, T_TOK / 128, E_NUM), 256, 0, stream>>>(
        hidden, w2, counts, offsets, idx_list, wgt_list, out);
  }
}

// Round 5
// 446.832 us; speedup vs baseline: 1.2113x; 1.2113x over previous
//
#include <hip/hip_runtime.h>
#include <hip/hip_bf16.h>
#include <stdint.h>

#define T_TOK 4096
#define H_DIM 1024
#define F_DIM 2816
#define E_NUM 8

typedef __attribute__((ext_vector_type(8))) __bf16 bf16x8;
typedef __attribute__((ext_vector_type(4))) float floatx4;
typedef __attribute__((address_space(3))) char lds_char;
typedef __attribute__((address_space(1))) const char glb_char;

// async 16B global->LDS (dest = wave-uniform base + lane*16)
__device__ __forceinline__ void gload16(const void* g, void* l) {
  __builtin_amdgcn_global_load_lds((glb_char*)g, (lds_char*)l, 16, 0, 0);
}

// round-to-nearest-even fp32 -> bf16, packed 2-at-a-time
__device__ __forceinline__ unsigned pack2bf16(float a, float b) {
  unsigned ua = __builtin_bit_cast(unsigned, a);
  unsigned ub = __builtin_bit_cast(unsigned, b);
  ua += 0x7fffu + ((ua >> 16) & 1u);
  ub += 0x7fffu + ((ub >> 16) & 1u);
  return (ua >> 16) | (ub & 0xffff0000u);
}

__device__ __forceinline__ float b2f(unsigned short u) {
  unsigned v = ((unsigned)u) << 16;
  return __builtin_bit_cast(float, v);
}

// XOR swizzle for [row][64 bf16] LDS tiles (128 B rows): proven 0-conflict in
// R3. colb is byte offset within the row.
__device__ __forceinline__ int swz(int row, int colb) {
  return (row * 128 + colb) ^ ((row & 7) << 4);
}

// ---------------- fp32 -> bf16 weight conversion (grid-stride) --------------
__global__ __launch_bounds__(256) void convert_kernel(
    const float* __restrict__ src, __hip_bfloat16* __restrict__ dst,
    int nchunk8) {
  int i = blockIdx.x * blockDim.x + threadIdx.x;
  const int stride = gridDim.x * blockDim.x;
  for (; i < nchunk8; i += stride) {
    const float4* s = (const float4*)(src + (size_t)i * 8);
    float4 a = s[0], b = s[1];
    uint4 p;
    p.x = pack2bf16(a.x, a.y); p.y = pack2bf16(a.z, a.w);
    p.z = pack2bf16(b.x, b.y); p.w = pack2bf16(b.z, b.w);
    *(uint4*)((char*)dst + (size_t)i * 16) = p;
  }
}

// ---- w1/w3 interleaved convert: wB[e][rho][h], rho in 32-row groups of
// ---- [16 rows w1 fblock | 16 rows w3 fblock];  f = (rho>>5)*16 + (rho&15).
__global__ __launch_bounds__(256) void convert_w13(
    const float* __restrict__ w1, const float* __restrict__ w3,
    __hip_bfloat16* __restrict__ wB) {
  const int e = blockIdx.y;
  const int rho = blockIdx.x * 2 + (threadIdx.x >> 7);
  const int hc = threadIdx.x & 127;                 // 8-float chunk in row
  const int f = ((rho >> 5) << 4) + (rho & 15);
  const float* src = ((rho >> 4) & 1 ? w3 : w1) +
                     ((size_t)e * F_DIM + f) * H_DIM + hc * 8;
  const float4* s = (const float4*)src;
  float4 a = s[0], b = s[1];
  uint4 p;
  p.x = pack2bf16(a.x, a.y); p.y = pack2bf16(a.z, a.w);
  p.z = pack2bf16(b.x, b.y); p.w = pack2bf16(b.z, b.w);
  *(uint4*)((char*)wB + (((size_t)e * (2 * F_DIM) + rho) * H_DIM + hc * 8) * 2)
      = p;
}

// ---------------- router ----------------------------------------------------
__global__ __launch_bounds__(256) void router_kernel(
    const float* __restrict__ x, const float* __restrict__ gate,
    float* __restrict__ logits_out, __hip_bfloat16* __restrict__ xb,
    int* __restrict__ counts, int* __restrict__ idx_list,
    float* __restrict__ wgt_list, int* __restrict__ meta0,
    int* __restrict__ meta1, float* __restrict__ wcomb)
{
  const int wv = threadIdx.x >> 6;
  const int lane = threadIdx.x & 63;
  const int t = blockIdx.x * 4 + wv;

  const float4* xr = (const float4*)(x + (size_t)t * H_DIM);
  const float4* g4 = (const float4*)gate;

  float acc[E_NUM];
#pragma unroll
  for (int e = 0; e < E_NUM; ++e) acc[e] = 0.f;

  unsigned* xbo = (unsigned*)(xb + (size_t)t * H_DIM);
#pragma unroll
  for (int j = 0; j < 4; ++j) {
    int i = j * 64 + lane;
    float4 xv = xr[i];
    uint2 pk;
    pk.x = pack2bf16(xv.x, xv.y);
    pk.y = pack2bf16(xv.z, xv.w);
    *(uint2*)(xbo + i * 2) = pk;
#pragma unroll
    for (int e = 0; e < E_NUM; ++e) {
      float4 gv = g4[e * 256 + i];
      acc[e] += xv.x * gv.x + xv.y * gv.y + xv.z * gv.z + xv.w * gv.w;
    }
  }
#pragma unroll
  for (int off = 32; off > 0; off >>= 1) {
#pragma unroll
    for (int e = 0; e < E_NUM; ++e) acc[e] += __shfl_xor(acc[e], off, 64);
  }

  if (lane == 0) {
#pragma unroll
    for (int e = 0; e < E_NUM; ++e) logits_out[(size_t)t * E_NUM + e] = acc[e];
    int i0 = 0; float v0 = acc[0];
#pragma unroll
    for (int e = 1; e < E_NUM; ++e) if (acc[e] > v0) { v0 = acc[e]; i0 = e; }
    int i1 = -1; float v1 = -1e30f;
#pragma unroll
    for (int e = 0; e < E_NUM; ++e)
      if (e != i0 && acc[e] > v1) { v1 = acc[e]; i1 = e; }
    float p1 = __expf(v1 - v0);
    float w0 = 1.f / (1.f + p1);
    float w1 = p1 / (1.f + p1);
    int pos0 = atomicAdd(&counts[i0], 1);
    idx_list[i0 * T_TOK + pos0] = t;
    wgt_list[i0 * T_TOK + pos0] = w0;
    int pos1 = atomicAdd(&counts[i1], 1);
    idx_list[i1 * T_TOK + pos1] = t;
    wgt_list[i1 * T_TOK + pos1] = w1;
    meta0[t] = (i0 << 16) | pos0;
    meta1[t] = (i1 << 16) | pos1;
    wcomb[t] = w0;
  }
}

__global__ void scan_kernel(const int* __restrict__ counts,
                            int* __restrict__ offsets) {
  if (threadIdx.x == 0) {
    int s = 0;
    for (int e = 0; e < E_NUM; ++e) { offsets[e] = s; s += counts[e]; }
  }
}

// ------------- GEMM1: 256x256 tile, 8 waves, BK=64, 2-phase counted vmcnt ---
// C = X @ wB^T over interleaved wB; silu(even frag)*odd frag in epilogue.
__global__ __launch_bounds__(512, 2) void gemm1_kernel(
    const __hip_bfloat16* __restrict__ xb,
    const __hip_bfloat16* __restrict__ wB,
    const int* __restrict__ counts, const int* __restrict__ offsets,
    const int* __restrict__ idx_list, __hip_bfloat16* __restrict__ hidden)
{
  const int e = blockIdx.z;
  const int n_e = counts[e];
  const int tm = blockIdx.y;
  if (n_e == 0 || tm * 256 >= n_e) return;
  const int tn = blockIdx.x;                  // 256 wB rows = 128 f
  const int off_e = offsets[e];

  __shared__ char lds[131072];
  char* sA = lds;                             // 2 x 32768
  char* sB = lds + 65536;                     // 2 x 32768

  const int tid = threadIdx.x;
  const int lane = tid & 63;
  const int wv = tid >> 6;                    // 0..7
  const int wrow = (wv >> 2) * 128;           // {0,128}
  const int wcol = (wv & 3) * 64;             // {0,64,128,192}
  const int csw = ((lane & 7) ^ (lane >> 3)) << 4;
  const int wvb = wv * 1024;

  size_t aoff[4];
#pragma unroll
  for (int i = 0; i < 4; ++i) {
    int r = i * 64 + wv * 8 + (lane >> 3);
    int pos = tm * 256 + r;
    int p = pos < n_e ? pos : n_e - 1;
    aoff[i] = (size_t)idx_list[e * T_TOK + p] * 2048;
  }
  const char* xbp = (const char*)xb;
  const char* wBp =
      (const char*)wB + ((size_t)e * (2 * F_DIM) + tn * 256) * 2048;
  size_t boff[4];
#pragma unroll
  for (int i = 0; i < 4; ++i)
    boff[i] = (size_t)(i * 64 + wv * 8 + (lane >> 3)) * 2048;

  floatx4 acc[8][4];
#pragma unroll
  for (int m = 0; m < 8; ++m)
#pragma unroll
    for (int n = 0; n < 4; ++n)
#pragma unroll
      for (int r = 0; r < 4; ++r) acc[m][n][r] = 0.f;

#define STAGE1(set, kb)                                                \
  do {                                                                 \
    char* dA = sA + (set) * 32768 + wvb;                               \
    char* dB = sB + (set) * 32768 + wvb;                               \
    _Pragma("unroll")                                                  \
    for (int i = 0; i < 4; ++i) {                                      \
      gload16(xbp + aoff[i] + (kb) + csw, dA + i * 8192);              \
      gload16(wBp + boff[i] + (kb) + csw, dB + i * 8192);              \
    }                                                                  \
  } while (0)

  // drain gather loads so counted vmcnt sees only our DMAs
  asm volatile("s_waitcnt vmcnt(0)" ::: "memory");
  STAGE1(0, 0);

  int cur = 0;
  for (int kt = 0; kt < H_DIM / 64; ++kt) {       // 16 K-tiles
    if (kt < H_DIM / 64 - 1) {
      STAGE1(cur ^ 1, (kt + 1) * 128);
      asm volatile("s_waitcnt vmcnt(8)" ::: "memory");  // this tile landed
    } else {
      asm volatile("s_waitcnt vmcnt(0)" ::: "memory");
    }
    __syncthreads();
    const char* rA = sA + cur * 32768;
    const char* rB = sB + cur * 32768;
#pragma unroll
    for (int kk = 0; kk < 2; ++kk) {
      const int colb = kk * 64 + (lane >> 4) * 16;
      bf16x8 af[8], bx[4];
#pragma unroll
      for (int m = 0; m < 8; ++m)
        af[m] = *(const bf16x8*)(rA + swz(wrow + m * 16 + (lane & 15), colb));
#pragma unroll
      for (int n = 0; n < 4; ++n)
        bx[n] = *(const bf16x8*)(rB + swz(wcol + n * 16 + (lane & 15), colb));
#pragma unroll
      for (int m = 0; m < 8; ++m)
#pragma unroll
        for (int n = 0; n < 4; ++n)
          acc[m][n] = __builtin_amdgcn_mfma_f32_16x16x32_bf16(
              af[m], bx[n], acc[m][n], 0, 0, 0);
    }
    __syncthreads();
    cur ^= 1;
  }
#undef STAGE1

  // epilogue: pair even/odd N-fragments (w1/w3 of same f-block), silu*mul
  const int fbase = (tn * 8 + (wcol >> 5)) * 16 + (lane & 15);
#pragma unroll
  for (int m = 0; m < 8; ++m) {
#pragma unroll
    for (int r = 0; r < 4; ++r) {
      int pos = tm * 256 + wrow + m * 16 + ((lane >> 4) << 2) + r;
      if (pos < n_e) {
        __hip_bfloat16* hrow = hidden + (size_t)(off_e + pos) * F_DIM;
#pragma unroll
        for (int j = 0; j < 2; ++j) {
          float h1 = acc[m][2 * j][r];
          float h3 = acc[m][2 * j + 1][r];
          float h = (h1 / (1.f + __expf(-h1))) * h3;   // silu(h1)*h3
          hrow[fbase + j * 16] = __float2bfloat16(h);
        }
      }
    }
  }
}

// ------------- GEMM2: 128x128 tile, 4 waves, BK=64, 2-phase counted vmcnt ---
// y = hidden @ W2^T (bf16 out, contiguous slots, no gather/scatter).
__global__ __launch_bounds__(256, 2) void gemm2_kernel(
    const __hip_bfloat16* __restrict__ hidden,
    const __hip_bfloat16* __restrict__ w2b,
    const int* __restrict__ counts, const int* __restrict__ offsets,
    __hip_bfloat16* __restrict__ y)
{
  const int e = blockIdx.z;
  const int n_e = counts[e];
  const int tm = blockIdx.y;
  if (n_e == 0 || tm * 128 >= n_e) return;
  const int tn = blockIdx.x;
  const int n0 = tn * 128;
  const int off_e = offsets[e];

  __shared__ char lds[65536];
  char* sA = lds;                             // 2 x 16384
  char* sB = lds + 32768;                     // 2 x 16384

  const int tid = threadIdx.x;
  const int lane = tid & 63;
  const int wv = tid >> 6;
  const int wrow = (wv >> 1) * 64;
  const int wcol = (wv & 1) * 64;
  const int csw = ((lane & 7) ^ (lane >> 3)) << 4;
  const int wvb = wv * 1024;

  size_t aoff[4], boff[4];
#pragma unroll
  for (int i = 0; i < 4; ++i) {
    int r = i * 32 + wv * 8 + (lane >> 3);
    int pos = tm * 128 + r;
    int p = pos < n_e ? pos : n_e - 1;
    aoff[i] = (size_t)(off_e + p) * (F_DIM * 2);
    boff[i] = ((size_t)e * H_DIM + n0 + r) * (F_DIM * 2);
  }
  const char* hp = (const char*)hidden;
  const char* w2p = (const char*)w2b;

  floatx4 acc[4][4];
#pragma unroll
  for (int m = 0; m < 4; ++m)
#pragma unroll
    for (int n = 0; n < 4; ++n)
#pragma unroll
      for (int r = 0; r < 4; ++r) acc[m][n][r] = 0.f;

#define STAGE2(set, kb)                                                \
  do {                                                                 \
    char* dA = sA + (set) * 16384 + wvb;                               \
    char* dB = sB + (set) * 16384 + wvb;                               \
    _Pragma("unroll")                                                  \
    for (int i = 0; i < 4; ++i) {                                      \
      gload16(hp + aoff[i] + (kb) + csw, dA + i * 4096);               \
      gload16(w2p + boff[i] + (kb) + csw, dB + i * 4096);              \
    }                                                                  \
  } while (0)

  asm volatile("s_waitcnt vmcnt(0)" ::: "memory");
  STAGE2(0, 0);

  int cur = 0;
  for (int kt = 0; kt < F_DIM / 64; ++kt) {       // 44 K-tiles
    if (kt < F_DIM / 64 - 1) {
      STAGE2(cur ^ 1, (kt + 1) * 128);
      asm volatile("s_waitcnt vmcnt(8)" ::: "memory");
    } else {
      asm volatile("s_waitcnt vmcnt(0)" ::: "memory");
    }
    __syncthreads();
    const char* rA = sA + cur * 16384;
    const char* rB = sB + cur * 16384;
#pragma unroll
    for (int kk = 0; kk < 2; ++kk) {
      const int colb = kk * 64 + (lane >> 4) * 16;
      bf16x8 af[4], bx[4];
#pragma unroll
      for (int m = 0; m < 4; ++m)
        af[m] = *(const bf16x8*)(rA + swz(wrow + m * 16 + (lane & 15), colb));
#pragma unroll
      for (int n = 0; n < 4; ++n)
        bx[n] = *(const bf16x8*)(rB + swz(wcol + n * 16 + (lane & 15), colb));
#pragma unroll
      for (int m = 0; m < 4; ++m)
#pragma unroll
        for (int n = 0; n < 4; ++n)
          acc[m][n] = __builtin_amdgcn_mfma_f32_16x16x32_bf16(
              af[m], bx[n], acc[m][n], 0, 0, 0);
    }
    __syncthreads();
    cur ^= 1;
  }
#undef STAGE2

#pragma unroll
  for (int m = 0; m < 4; ++m) {
#pragma unroll
    for (int r = 0; r < 4; ++r) {
      int pos = tm * 128 + wrow + m * 16 + ((lane >> 4) << 2) + r;
      if (pos < n_e) {
        __hip_bfloat16* yrow = y + (size_t)(off_e + pos) * H_DIM + n0;
#pragma unroll
        for (int n = 0; n < 4; ++n)
          yrow[wcol + n * 16 + (lane & 15)] = __float2bfloat16(acc[m][n][r]);
      }
    }
  }
}

// ------------- combine: out[t] = w0*y[slot0] + (1-w0)*y[slot1] --------------
__global__ __launch_bounds__(256) void combine_kernel(
    const __hip_bfloat16* __restrict__ y, const int* __restrict__ offsets,
    const int* __restrict__ meta0, const int* __restrict__ meta1,
    const float* __restrict__ wcomb, float* __restrict__ out)
{
  const int t = blockIdx.x;
  const int m0 = meta0[t], m1 = meta1[t];
  const float w0 = wcomb[t];
  const float w1 = 1.f - w0;
  const size_t s0 = (size_t)(offsets[m0 >> 16] + (m0 & 0xffff)) * H_DIM;
  const size_t s1 = (size_t)(offsets[m1 >> 16] + (m1 & 0xffff)) * H_DIM;
  const int c = threadIdx.x * 4;
  ushort4 a = *(const ushort4*)(y + s0 + c);
  ushort4 b = *(const ushort4*)(y + s1 + c);
  float4 o;
  o.x = w0 * b2f(a.x) + w1 * b2f(b.x);
  o.y = w0 * b2f(a.y) + w1 * b2f(b.y);
  o.z = w0 * b2f(a.z) + w1 * b2f(b.z);
  o.w = w0 * b2f(a.w) + w1 * b2f(b.w);
  *(float4*)(out + (size_t)t * H_DIM + c) = o;
}

// =================== fallback path (round-1 kernels, fused convert) =========
__global__ __launch_bounds__(256) void gemm1_fb(
    const __hip_bfloat16* __restrict__ xb,
    const float* __restrict__ w1, const float* __restrict__ w3,
    const int* __restrict__ counts, const int* __restrict__ offsets,
    const int* __restrict__ idx_list, __hip_bfloat16* __restrict__ hidden)
{
  const int e = blockIdx.z;
  const int n_e = counts[e];
  const int tm = blockIdx.y;
  if (n_e == 0 || tm * 128 >= n_e) return;
  const int tn = blockIdx.x;
  const int f0 = tn * 128;
  const int off_e = offsets[e];

  __shared__ short sA[128 * 64];
  __shared__ short sB1[128 * 64];
  __shared__ short sB3[128 * 64];
  __shared__ int s_row[128];

  const int tid = threadIdx.x;
  if (tid < 128) {
    int pos = tm * 128 + tid;
    int p = pos < n_e ? pos : n_e - 1;
    s_row[tid] = idx_list[e * T_TOK + p];
  }
  const int lane = tid & 63;
  const int wv = tid >> 6;
  const int wrow = (wv >> 1) * 64;
  const int wcol = (wv & 1) * 64;
  const int cc = tid & 7;
  const int rbase = tid >> 3;

  floatx4 acc1[4][4], acc3[4][4];
#pragma unroll
  for (int m = 0; m < 4; ++m)
#pragma unroll
    for (int n = 0; n < 4; ++n)
#pragma unroll
      for (int r = 0; r < 4; ++r) { acc1[m][n][r] = 0.f; acc3[m][n][r] = 0.f; }

  const float* w1e = w1 + (size_t)e * F_DIM * H_DIM + (size_t)f0 * H_DIM;
  const float* w3e = w3 + (size_t)e * F_DIM * H_DIM + (size_t)f0 * H_DIM;

  for (int kt = 0; kt < H_DIM / 64; ++kt) {
    const int k0 = kt * 64;
    __syncthreads();
#pragma unroll
    for (int i = 0; i < 4; ++i) {
      int r = rbase + 32 * i;
      uint4 av = *(const uint4*)(xb + (size_t)s_row[r] * H_DIM + k0 + cc * 8);
      *(uint4*)((char*)sA + swz(r, cc * 16)) = av;
      const float4* p1 = (const float4*)(w1e + (size_t)r * H_DIM + k0 + cc * 8);
      float4 a1 = p1[0], b1 = p1[1];
      uint4 pb1;
      pb1.x = pack2bf16(a1.x, a1.y); pb1.y = pack2bf16(a1.z, a1.w);
      pb1.z = pack2bf16(b1.x, b1.y); pb1.w = pack2bf16(b1.z, b1.w);
      *(uint4*)((char*)sB1 + swz(r, cc * 16)) = pb1;
      const float4* p3 = (const float4*)(w3e + (size_t)r * H_DIM + k0 + cc * 8);
      float4 a3 = p3[0], b3 = p3[1];
      uint4 pb3;
      pb3.x = pack2bf16(a3.x, a3.y); pb3.y = pack2bf16(a3.z, a3.w);
      pb3.z = pack2bf16(b3.x, b3.y); pb3.w = pack2bf16(b3.z, b3.w);
      *(uint4*)((char*)sB3 + swz(r, cc * 16)) = pb3;
    }
    __syncthreads();
#pragma unroll
    for (int kk = 0; kk < 2; ++kk) {
      const int colb = kk * 64 + (lane >> 4) * 16;
      bf16x8 af[4], bf1[4], bf3[4];
#pragma unroll
      for (int m = 0; m < 4; ++m)
        af[m] = *(const bf16x8*)((const char*)sA +
                                 swz(wrow + m * 16 + (lane & 15), colb));
#pragma unroll
      for (int n = 0; n < 4; ++n) {
        bf1[n] = *(const bf16x8*)((const char*)sB1 +
                                  swz(wcol + n * 16 + (lane & 15), colb));
        bf3[n] = *(const bf16x8*)((const char*)sB3 +
                                  swz(wcol + n * 16 + (lane & 15), colb));
      }
#pragma unroll
      for (int m = 0; m < 4; ++m)
#pragma unroll
        for (int n = 0; n < 4; ++n) {
          acc1[m][n] = __builtin_amdgcn_mfma_f32_16x16x32_bf16(
              af[m], bf1[n], acc1[m][n], 0, 0, 0);
          acc3[m][n] = __builtin_amdgcn_mfma_f32_16x16x32_bf16(
              af[m], bf3[n], acc3[m][n], 0, 0, 0);
        }
    }
  }
#pragma unroll
  for (int m = 0; m < 4; ++m) {
#pragma unroll
    for (int r = 0; r < 4; ++r) {
      int rl = wrow + m * 16 + ((lane >> 4) << 2) + r;
      int pos = tm * 128 + rl;
      if (pos < n_e) {
        __hip_bfloat16* hrow = hidden + (size_t)(off_e + pos) * F_DIM + f0;
#pragma unroll
        for (int n = 0; n < 4; ++n) {
          float h1 = acc1[m][n][r];
          float h3 = acc3[m][n][r];
          float h = (h1 / (1.f + __expf(-h1))) * h3;
          hrow[wcol + n * 16 + (lane & 15)] = __float2bfloat16(h);
        }
      }
    }
  }
}

__global__ __launch_bounds__(256) void gemm2_fb(
    const __hip_bfloat16* __restrict__ hidden, const float* __restrict__ w2,
    const int* __restrict__ counts, const int* __restrict__ offsets,
    const int* __restrict__ idx_list, const float* __restrict__ wgt_list,
    float* __restrict__ out)
{
  const int e = blockIdx.z;
  const int n_e = counts[e];
  const int tm = blockIdx.y;
  if (n_e == 0 || tm * 128 >= n_e) return;
  const int tn = blockIdx.x;
  const int n0 = tn * 128;
  const int off_e = offsets[e];

  __shared__ short sA[128 * 64];
  __shared__ short sB[128 * 64];
  __shared__ int s_tok[128];
  __shared__ float s_wgt[128];

  const int tid = threadIdx.x;
  if (tid < 128) {
    int pos = tm * 128 + tid;
    if (pos < n_e) {
      s_tok[tid] = idx_list[e * T_TOK + pos];
      s_wgt[tid] = wgt_list[e * T_TOK + pos];
    } else {
      s_tok[tid] = -1;
      s_wgt[tid] = 0.f;
    }
  }
  const int lane = tid & 63;
  const int wv = tid >> 6;
  const int wrow = (wv >> 1) * 64;
  const int wcol = (wv & 1) * 64;
  const int cc = tid & 7;
  const int rbase = tid >> 3;

  floatx4 acc[4][4];
#pragma unroll
  for (int m = 0; m < 4; ++m)
#pragma unroll
    for (int n = 0; n < 4; ++n)
#pragma unroll
      for (int r = 0; r < 4; ++r) acc[m][n][r] = 0.f;

  const float* w2e = w2 + (size_t)e * H_DIM * F_DIM + (size_t)n0 * F_DIM;

  for (int kt = 0; kt < F_DIM / 64; ++kt) {
    const int k0 = kt * 64;
    __syncthreads();
#pragma unroll
    for (int i = 0; i < 4; ++i) {
      int r = rbase + 32 * i;
      int pos = tm * 128 + r;
      int pr = pos < n_e ? pos : n_e - 1;
      uint4 av = *(const uint4*)(hidden + (size_t)(off_e + pr) * F_DIM +
                                 k0 + cc * 8);
      *(uint4*)((char*)sA + swz(r, cc * 16)) = av;
      const float4* pb = (const float4*)(w2e + (size_t)r * F_DIM + k0 + cc * 8);
      float4 ba = pb[0], bb = pb[1];
      uint4 pk;
      pk.x = pack2bf16(ba.x, ba.y); pk.y = pack2bf16(ba.z, ba.w);
      pk.z = pack2bf16(bb.x, bb.y); pk.w = pack2bf16(bb.z, bb.w);
      *(uint4*)((char*)sB + swz(r, cc * 16)) = pk;
    }
    __syncthreads();
#pragma unroll
    for (int kk = 0; kk < 2; ++kk) {
      const int colb = kk * 64 + (lane >> 4) * 16;
      bf16x8 af[4], bf[4];
#pragma unroll
      for (int m = 0; m < 4; ++m)
        af[m] = *(const bf16x8*)((const char*)sA +
                                 swz(wrow + m * 16 + (lane & 15), colb));
#pragma unroll
      for (int n = 0; n < 4; ++n)
        bf[n] = *(const bf16x8*)((const char*)sB +
                                 swz(wcol + n * 16 + (lane & 15), colb));
#pragma unroll
      for (int m = 0; m < 4; ++m)
#pragma unroll
        for (int n = 0; n < 4; ++n)
          acc[m][n] = __builtin_amdgcn_mfma_f32_16x16x32_bf16(
              af[m], bf[n], acc[m][n], 0, 0, 0);
    }
  }
#pragma unroll
  for (int m = 0; m < 4; ++m) {
#pragma unroll
    for (int r = 0; r < 4; ++r) {
      int rl = wrow + m * 16 + ((lane >> 4) << 2) + r;
      int tok = s_tok[rl];
      if (tok >= 0) {
        float wgt = s_wgt[rl];
        float* orow = out + (size_t)tok * H_DIM + n0;
#pragma unroll
        for (int n = 0; n < 4; ++n)
          atomicAdd(&orow[wcol + n * 16 + (lane & 15)], wgt * acc[m][n][r]);
      }
    }
  }
}

extern "C" void kernel_launch(void* const* d_in, const int* in_sizes, int n_in,
                              void* d_out, int out_size, void* d_ws,
                              size_t ws_size, hipStream_t stream) {
  const float* x = (const float*)d_in[0];
  const float* gate = (const float*)d_in[1];
  const float* w1 = (const float*)d_in[2];
  const float* w3 = (const float*)d_in[3];
  const float* w2 = (const float*)d_in[4];

  float* out = (float*)d_out;                        // [T, H]
  float* logits = out + (size_t)T_TOK * H_DIM;       // [T, E]

  char* ws = (char*)d_ws;
  const size_t o_idx = 256;
  const size_t o_wgt = o_idx + (size_t)E_NUM * T_TOK * 4;
  const size_t o_m0  = o_wgt + (size_t)E_NUM * T_TOK * 4;
  const size_t o_m1  = o_m0 + (size_t)T_TOK * 4;
  const size_t o_wc  = o_m1 + (size_t)T_TOK * 4;
  const size_t o_xb  = o_wc + (size_t)T_TOK * 4;
  const size_t o_hid = o_xb + (size_t)T_TOK * H_DIM * 2;
  const size_t o_wB  = o_hid + (size_t)2 * T_TOK * F_DIM * 2;
  const size_t o_w2b = o_wB + (size_t)E_NUM * 2 * F_DIM * H_DIM * 2;
  const size_t need  = o_w2b + (size_t)E_NUM * H_DIM * F_DIM * 2;  // ~184 MiB

  int* counts = (int*)ws;
  int* offsets = counts + 8;
  int* idx_list = (int*)(ws + o_idx);
  float* wgt_list = (float*)(ws + o_wgt);
  int* meta0 = (int*)(ws + o_m0);
  int* meta1 = (int*)(ws + o_m1);
  float* wcomb = (float*)(ws + o_wc);
  __hip_bfloat16* xb = (__hip_bfloat16*)(ws + o_xb);
  __hip_bfloat16* hidden = (__hip_bfloat16*)(ws + o_hid);

  hipMemsetAsync(counts, 0, 64, stream);

  if (ws_size >= need) {
    __hip_bfloat16* wB = (__hip_bfloat16*)(ws + o_wB);
    __hip_bfloat16* w2b = (__hip_bfloat16*)(ws + o_w2b);
    __hip_bfloat16* y = (__hip_bfloat16*)(ws + o_wB);   // alias: wB dead then

    convert_w13<<<dim3(F_DIM, E_NUM), 256, 0, stream>>>(w1, w3, wB);
    convert_kernel<<<2048, 256, 0, stream>>>(
        w2, w2b, E_NUM * F_DIM * H_DIM / 8);
    router_kernel<<<T_TOK / 4, 256, 0, stream>>>(
        x, gate, logits, xb, counts, idx_list, wgt_list, meta0, meta1, wcomb);
    scan_kernel<<<1, 64, 0, stream>>>(counts, offsets);
    gemm1_kernel<<<dim3(2 * F_DIM / 256, T_TOK / 256, E_NUM), 512, 0,
                   stream>>>(xb, wB, counts, offsets, idx_list, hidden);
    gemm2_kernel<<<dim3(H_DIM / 128, T_TOK / 128, E_NUM), 256, 0, stream>>>(
        hidden, w2b, counts, offsets, y);
    combine_kernel<<<T_TOK, 256, 0, stream>>>(y, offsets, meta0, meta1, wcomb,
                                              out);
  } else {
    hipMemsetAsync(out, 0, (size_t)T_TOK * H_DIM * sizeof(float), stream);
    router_kernel<<<T_TOK / 4, 256, 0, stream>>>(
        x, gate, logits, xb, counts, idx_list, wgt_list, meta0, meta1, wcomb);
    scan_kernel<<<1, 64, 0, stream>>>(counts, offsets);
    gemm1_fb<<<dim3(F_DIM / 128, T_TOK / 128, E_NUM), 256, 0, stream>>>(
        xb, w1, w3, counts, offsets, idx_list, hidden);
    gemm2_fb<<<dim3(H_DIM / 128, T_TOK / 128, E_NUM), 256, 0, stream>>>(
        hidden, w2, counts, offsets, idx_list, wgt_list, out);
  }
}